// Round 1
// baseline (1305.316 us; speedup 1.0000x reference)
//
#include <hip/hip_runtime.h>

// Problem constants
#define Nn 50000
#define Ee 625000
#define INDIM 128
#define NH 8
#define HDIM 16
// H*D = 128 output cols; K = 128

typedef __attribute__((ext_vector_type(8))) short short8;
typedef __attribute__((ext_vector_type(4))) float floatx4;

#define LDS_STRIDE 136  // 128 + 8 pad: frag reads land 2-way bank aliased (free)

__device__ inline unsigned short f2bf(float f) {
    unsigned u = __builtin_bit_cast(unsigned, f);
    u = (u + 0x7FFFu + ((u >> 16) & 1u)) >> 16;  // round-to-nearest-even
    return (unsigned short)u;
}

// Stage a 128-row x 128-col fp32 tile -> bf16 LDS [row][col], stride 136, zero-pad invalid rows
__device__ inline void stage_tile_bf16(const float* __restrict__ g, long row0, long nrows_total,
                                       unsigned short* lds, int tid) {
    for (int it = 0; it < 16; ++it) {
        int r = it * 8 + (tid >> 5);
        int c4 = (tid & 31) * 4;
        float4 v = make_float4(0.f, 0.f, 0.f, 0.f);
        long gr = row0 + r;
        if (gr < nrows_total) {
            v = *reinterpret_cast<const float4*>(g + gr * 128 + c4);
        }
        ushort4 o;
        o.x = f2bf(v.x); o.y = f2bf(v.y); o.z = f2bf(v.z); o.w = f2bf(v.w);
        *reinterpret_cast<ushort4*>(lds + r * LDS_STRIDE + c4) = o;
    }
}

// Stage W[k][n] (128x128 row-major) transposed into LDS as Wt[n][k], bf16, stride 136
__device__ inline void stage_w_t(const float* __restrict__ W, unsigned short* lds, int tid) {
    for (int it = 0; it < 64; ++it) {
        int idx = it * 256 + tid;
        int k = idx >> 7, n = idx & 127;
        lds[n * LDS_STRIDE + k] = f2bf(W[idx]);
    }
}

// ---------------- Node projections: Q/K/V = h @ W + b ----------------
__global__ __launch_bounds__(256) void node_qkv(
    const float* __restrict__ h,
    const float* __restrict__ Wq, const float* __restrict__ bq,
    const float* __restrict__ Wk, const float* __restrict__ bk,
    const float* __restrict__ Wv, const float* __restrict__ bv,
    float* __restrict__ Q, float* __restrict__ K, float* __restrict__ V) {
    __shared__ unsigned short ht[128 * LDS_STRIDE];
    __shared__ unsigned short wt[128 * LDS_STRIDE];
    int tid = threadIdx.x;
    long n0 = (long)blockIdx.x * 128;
    stage_tile_bf16(h, n0, Nn, ht, tid);
    __syncthreads();

    int wave = tid >> 6, lane = tid & 63;
    int q4 = lane >> 4, col = lane & 15;

    // preload A fragments: wave handles m-tiles {2w, 2w+1} (16 nodes each)
    short8 afr[2][4];
    for (int t = 0; t < 2; ++t) {
        int mrow = (wave * 2 + t) * 16 + col;
        for (int kc = 0; kc < 4; ++kc)
            afr[t][kc] = *reinterpret_cast<const short8*>(&ht[mrow * LDS_STRIDE + kc * 32 + q4 * 8]);
    }

    const float* Wm[3] = {Wq, Wk, Wv};
    const float* bm[3] = {bq, bk, bv};
    float* Om[3] = {Q, K, V};

    for (int mat = 0; mat < 3; ++mat) {
        __syncthreads();  // previous compute done reading wt
        stage_w_t(Wm[mat], wt, tid);
        __syncthreads();
        for (int n = 0; n < 8; ++n) {
            short8 bfr[4];
            for (int kc = 0; kc < 4; ++kc)
                bfr[kc] = *reinterpret_cast<const short8*>(&wt[(n * 16 + col) * LDS_STRIDE + kc * 32 + q4 * 8]);
            float bias = bm[mat][n * 16 + col];
            for (int t = 0; t < 2; ++t) {
                floatx4 acc = {0.f, 0.f, 0.f, 0.f};
                for (int kc = 0; kc < 4; ++kc)
                    acc = __builtin_amdgcn_mfma_f32_16x16x32_bf16(afr[t][kc], bfr[kc], acc, 0, 0, 0);
                for (int r = 0; r < 4; ++r) {
                    long node = n0 + (wave * 2 + t) * 16 + q4 * 4 + r;
                    if (node < Nn) Om[mat][node * 128 + n * 16 + col] = acc[r] + bias;
                }
            }
        }
    }
}

// ---------------- Fused edge kernel: pe GEMM + score + e_out + s + atomics ----------------
__global__ __launch_bounds__(256) void edge_fused(
    const float* __restrict__ e, const int* __restrict__ src, const int* __restrict__ dst,
    const float* __restrict__ We, const float* __restrict__ be,
    const float* __restrict__ Q, const float* __restrict__ K, const float* __restrict__ V,
    float* __restrict__ e_out, float* __restrict__ hacc, float* __restrict__ z) {
    __shared__ unsigned short et[128 * LDS_STRIDE];
    __shared__ unsigned short wt[128 * LDS_STRIDE];
    __shared__ int ssrc[128];
    __shared__ int sdst[128];
    int tid = threadIdx.x;
    long e0 = (long)blockIdx.x * 128;
    stage_tile_bf16(e, e0, Ee, et, tid);
    stage_w_t(We, wt, tid);
    if (tid < 128) {
        long ge = e0 + tid;
        ssrc[tid] = (ge < Ee) ? src[ge] : 0;
        sdst[tid] = (ge < Ee) ? dst[ge] : 0;
    }
    __syncthreads();

    int wave = tid >> 6, lane = tid & 63;
    int q4 = lane >> 4, col = lane & 15;

    short8 afr[2][4];
    for (int t = 0; t < 2; ++t) {
        int mrow = (wave * 2 + t) * 16 + col;
        for (int kc = 0; kc < 4; ++kc)
            afr[t][kc] = *reinterpret_cast<const short8*>(&et[mrow * LDS_STRIDE + kc * 32 + q4 * 8]);
    }

    for (int head = 0; head < 8; ++head) {
        short8 bfr[4];
        for (int kc = 0; kc < 4; ++kc)
            bfr[kc] = *reinterpret_cast<const short8*>(&wt[(head * 16 + col) * LDS_STRIDE + kc * 32 + q4 * 8]);
        int hoff = head * 16 + col;
        float bias = be[hoff];
        for (int t = 0; t < 2; ++t) {
            floatx4 acc = {0.f, 0.f, 0.f, 0.f};
            for (int kc = 0; kc < 4; ++kc)
                acc = __builtin_amdgcn_mfma_f32_16x16x32_bf16(afr[t][kc], bfr[kc], acc, 0, 0, 0);
            int mt = wave * 2 + t;
            for (int r = 0; r < 4; ++r) {
                int el = mt * 16 + q4 * 4 + r;  // local edge 0..127
                long ge = e0 + el;
                bool valid = ge < Ee;
                int s32 = ssrc[el], d32 = sdst[el];
                float pe = acc[r] + bias;
                float kv = K[s32 * 128 + hoff];
                float qv = Q[d32 * 128 + hoff];
                float score = kv * qv * 0.25f * pe;  // 1/sqrt(16)
                if (valid) e_out[ge * 128 + hoff] = score;
                // sum over the 16 head dims = butterfly across the 16 lanes of this quad
                float sum = score;
                sum += __shfl_xor(sum, 1, 16);
                sum += __shfl_xor(sum, 2, 16);
                sum += __shfl_xor(sum, 4, 16);
                sum += __shfl_xor(sum, 8, 16);
                float sval = __expf(fminf(fmaxf(sum, -5.0f), 5.0f));
                if (valid) {
                    float vv = V[s32 * 128 + hoff];
                    atomicAdd(&hacc[d32 * 128 + hoff], vv * sval);
                    if (col == 0) atomicAdd(&z[d32 * 8 + head], sval);
                }
            }
        }
    }
}

// ---------------- Finalize: h_out = acc / (z + 1e-6) ----------------
__global__ __launch_bounds__(256) void finalize(float* __restrict__ hacc, const float* __restrict__ z) {
    int i = blockIdx.x * 256 + threadIdx.x;
    int base = i * 4;  // 4 consecutive d within one head
    if (base < Nn * 128) {
        float4 a = *reinterpret_cast<float4*>(&hacc[base]);
        int node = base >> 7;
        int head = (base >> 4) & 7;
        float inv = 1.0f / (z[node * 8 + head] + 1e-6f);
        a.x *= inv; a.y *= inv; a.z *= inv; a.w *= inv;
        *reinterpret_cast<float4*>(&hacc[base]) = a;
    }
}

extern "C" void kernel_launch(void* const* d_in, const int* in_sizes, int n_in,
                              void* d_out, int out_size, void* d_ws, size_t ws_size,
                              hipStream_t stream) {
    const float* h  = (const float*)d_in[0];
    const float* e  = (const float*)d_in[1];
    const int*   src = (const int*)d_in[2];
    const int*   dst = (const int*)d_in[3];
    const float* Wq = (const float*)d_in[4];  const float* bq = (const float*)d_in[5];
    const float* Wk = (const float*)d_in[6];  const float* bk = (const float*)d_in[7];
    const float* Wv = (const float*)d_in[8];  const float* bv = (const float*)d_in[9];
    const float* We = (const float*)d_in[10]; const float* be = (const float*)d_in[11];

    float* out  = (float*)d_out;
    float* hout = out;                          // [N, H*D] = 6.4M floats
    float* eout = out + (size_t)Nn * 128;       // [E, H*D] = 80M floats

    float* ws = (float*)d_ws;                   // needs 78.4 MB
    float* Q = ws;
    float* K = ws + (size_t)Nn * 128;
    float* V = ws + 2 * (size_t)Nn * 128;
    float* z = ws + 3 * (size_t)Nn * 128;       // [N, H]

    hipMemsetAsync(hout, 0, (size_t)Nn * 128 * sizeof(float), stream);
    hipMemsetAsync(z, 0, (size_t)Nn * NH * sizeof(float), stream);

    node_qkv<<<(Nn + 127) / 128, 256, 0, stream>>>(h, Wq, bq, Wk, bk, Wv, bv, Q, K, V);
    edge_fused<<<(Ee + 127) / 128, 256, 0, stream>>>(e, src, dst, We, be, Q, K, V, eout, hout, z);
    finalize<<<(Nn * 128 / 4 + 255) / 256, 256, 0, stream>>>(hout, z);
}